// Round 7
// baseline (450.539 us; speedup 1.0000x reference)
//
#include <hip/hip_runtime.h>

// ---------------------------------------------------------------------------
// GCN 2-layer forward on MI355X.
// out = relu(Ahat * relu((Ahat*X)*W1 + b1) * W2 + b2),  Ahat = D^-1/2 (A+I) D^-1/2
// R1: multi-block scan. R2: agg unroll-8; 128x128 fp32 GEMM.
// R3: GEMMs -> bf16-split MFMA (Ootomo 3-mult), packed (hi<<16|lo) operands.
// R4: agg gathers bf16 (halved bytes; FETCH halved but time flat -> not byte-bound).
// R5: XCD-sliced agg: 4 x 32-col cacheline slices, blockIdx%8 = XCD round-robin
//     -> 3.2MB/XCD footprint (L2-resident); 4 edges/gather-inst; unroll-2.
// R6 FIX: self-loop term was added in all 4 edge-groups then shfl-summed (4x
//     overcount -> absmax 3.375). Now weighted by (g==0).
// ---------------------------------------------------------------------------

#define C_IN   128
#define C_HID  256
#define C_OUT  128

typedef __attribute__((ext_vector_type(8))) short short8;
typedef __attribute__((ext_vector_type(4))) float floatx4;

__device__ __forceinline__ unsigned short f2bf(float f) {
    unsigned u = __float_as_uint(f);
    u += 0x7FFFu + ((u >> 16) & 1u);      // RNE
    return (unsigned short)(u >> 16);
}
__device__ __forceinline__ float bf2f(unsigned short b) {
    return __uint_as_float(((unsigned)b) << 16);
}
__device__ __forceinline__ unsigned pack_hilo(float f) {
    unsigned short hi = f2bf(f);
    unsigned short lo = f2bf(f - bf2f(hi));
    return ((unsigned)hi << 16) | (unsigned)lo;
}
__device__ __forceinline__ float bflo(unsigned v) {   // low short as bf16->f32
    return __uint_as_float((v & 0xFFFFu) << 16);
}
__device__ __forceinline__ float bfhi(unsigned v) {   // high short as bf16->f32
    return __uint_as_float(v & 0xFFFF0000u);
}

// ---------------- degree histogram ----------------
__global__ void deg_kernel(const int* __restrict__ dst, int* __restrict__ counts, int E) {
    int e = blockIdx.x * blockDim.x + threadIdx.x;
    if (e < E) atomicAdd(&counts[dst[e]], 1);
}

// ---------------- multi-block scan: 1024 counts per block ----------------
#define SCHUNK 1024

__global__ __launch_bounds__(256) void scan_reduce(const int* __restrict__ counts,
                                                   int* __restrict__ block_sums, int n) {
    int b = blockIdx.x;
    int base = b * SCHUNK;
    int t = threadIdx.x;
    int s = 0;
    #pragma unroll
    for (int u = 0; u < 4; ++u) {
        int i = base + t * 4 + u;
        if (i < n) s += counts[i];
    }
    #pragma unroll
    for (int off = 32; off; off >>= 1) s += __shfl_down(s, off, 64);
    __shared__ int ws[4];
    int wave = t >> 6;
    if ((t & 63) == 0) ws[wave] = s;
    __syncthreads();
    if (t == 0) block_sums[b] = ws[0] + ws[1] + ws[2] + ws[3];
}

__global__ __launch_bounds__(64) void scan_sums(const int* __restrict__ block_sums,
                                                int* __restrict__ block_base, int nb,
                                                int* __restrict__ offsets, int n, int E) {
    int t = threadIdx.x;
    int v = (t < nb) ? block_sums[t] : 0;
    int x = v;
    #pragma unroll
    for (int off = 1; off < 64; off <<= 1) {
        int y = __shfl_up(x, off, 64);
        if (t >= off) x += y;
    }
    if (t < nb) block_base[t] = x - v;
    if (t == 0) offsets[n] = E;
}

__global__ __launch_bounds__(256) void scan_apply(const int* __restrict__ counts,
                                                  const int* __restrict__ block_base,
                                                  int* __restrict__ offsets,
                                                  int* __restrict__ cursor,
                                                  float* __restrict__ dinv, int n) {
    int b = blockIdx.x;
    int base_i = b * SCHUNK;
    int t = threadIdx.x;
    int c[4];
    #pragma unroll
    for (int u = 0; u < 4; ++u) {
        int i = base_i + t * 4 + u;
        c[u] = (i < n) ? counts[i] : 0;
    }
    int tot = c[0] + c[1] + c[2] + c[3];
    int x = tot;
    int lane = t & 63;
    #pragma unroll
    for (int off = 1; off < 64; off <<= 1) {
        int y = __shfl_up(x, off, 64);
        if (lane >= off) x += y;
    }
    __shared__ int ws[4];
    int wave = t >> 6;
    if (lane == 63) ws[wave] = x;
    __syncthreads();
    int wbase = 0;
    for (int w = 0; w < wave; ++w) wbase += ws[w];
    int run = block_base[b] + wbase + (x - tot);
    #pragma unroll
    for (int u = 0; u < 4; ++u) {
        int i = base_i + t * 4 + u;
        if (i < n) {
            offsets[i] = run;
            cursor[i]  = run;
            dinv[i]    = rsqrtf((float)(c[u] + 1));   // +1 self-loop
            run += c[u];
        }
    }
}

__global__ void fill_csr(const int* __restrict__ src, const int* __restrict__ dst,
                         int* __restrict__ cursor, int* __restrict__ csr_src, int E) {
    int e = blockIdx.x * blockDim.x + threadIdx.x;
    if (e < E) {
        int p = atomicAdd(&cursor[dst[e]], 1);
        csr_src[p] = src[e];
    }
}

// ---------------- weight cast+transpose: W[K][N] f32 -> Wt[N][K] packed ----
__global__ void cast_w_t(const float* __restrict__ W, unsigned* __restrict__ Wtp,
                         int K, int N) {
    int idx = blockIdx.x * blockDim.x + threadIdx.x;
    if (idx < K * N) {
        int k = idx / N, nn = idx - k * N;
        Wtp[(size_t)nn * K + k] = pack_hilo(W[idx]);
    }
}

// ---------------- x -> bf16 cast, 4 elems/thread ----------------
__global__ void cast_x_bf16(const float* __restrict__ x, unsigned* __restrict__ xb2,
                            int count4) {
    int idx = blockIdx.x * blockDim.x + threadIdx.x;
    if (idx < count4) {
        float4 f = ((const float4*)x)[idx];
        unsigned lo = (unsigned)f2bf(f.x) | ((unsigned)f2bf(f.y) << 16);
        unsigned hi = (unsigned)f2bf(f.z) | ((unsigned)f2bf(f.w) << 16);
        ((uint2*)xb2)[idx] = make_uint2(lo, hi);
    }
}

// ---------------- XCD-sliced pull aggregation: bf16 gather, fp32 accum -----
// 4 column-slices of 32 cols (64B, cacheline-aligned). blockIdx&7: slice=&3,
// sub=>>2 (two XCDs per slice); wave = one node's slice. Lane = 16*g + c:
// edge-group g (4 edges/inst), uint c (2 cols). Cross-group combine via
// shfl_xor(16/32). Self term enters via g==0 only (R6 fix).
// csr_src has >=8 ints slack past E.
__global__ __launch_bounds__(256) void agg_slice_kernel(
        const unsigned short* __restrict__ hb, const int* __restrict__ offsets,
        const int* __restrict__ csr_src, const float* __restrict__ dinv,
        const float* __restrict__ bias, float* __restrict__ out_f,
        unsigned* __restrict__ out_p, int relu_flag, int n) {
    int xb7  = blockIdx.x & 7;
    int slice = xb7 & 3;
    int node = (blockIdx.x >> 3) * 8 + (xb7 >> 2) * 4 + (threadIdx.x >> 6);
    if (node >= n) return;
    int lane = threadIdx.x & 63;
    int g = lane >> 4;                 // edge-group 0..3
    int c = lane & 15;                 // uint within 64B slice
    int sloff = slice * 16 + c;        // uint offset within 64-uint row
    int col0 = slice * 32 + c * 2;

    const unsigned* hrow = (const unsigned*)hb;   // row j = 64 uints

    float di = dinv[node];
    float selfw = (g == 0) ? di : 0.0f;          // self term counted ONCE (R6 fix)
    unsigned sv = hrow[(size_t)node * 64 + sloff];
    float a0 = selfw * bflo(sv);
    float a1 = selfw * bfhi(sv);

    int lo = offsets[node], hi = offsets[node + 1];
    for (int k = lo; k < hi; k += 8) {
        int k1 = k + g, k2 = k + 4 + g;
        int j1 = csr_src[k1];                     // slack past E covers overrun
        int j2 = csr_src[k2];
        bool ok1 = k1 < hi, ok2 = k2 < hi;
        j1 = ok1 ? j1 : 0;
        j2 = ok2 ? j2 : 0;
        float w1 = ok1 ? dinv[j1] : 0.0f;
        float w2 = ok2 ? dinv[j2] : 0.0f;
        unsigned v1 = hrow[(size_t)j1 * 64 + sloff];
        unsigned v2 = hrow[(size_t)j2 * 64 + sloff];
        __builtin_amdgcn_sched_barrier(0);        // loads stay issued before FMAs
        a0 += w1 * bflo(v1);  a1 += w1 * bfhi(v1);
        a0 += w2 * bflo(v2);  a1 += w2 * bfhi(v2);
    }

    // combine edge-groups: xor16 (g bit0), xor32 (g bit1)
    a0 += __shfl_xor(a0, 16, 64);  a1 += __shfl_xor(a1, 16, 64);
    a0 += __shfl_xor(a0, 32, 64);  a1 += __shfl_xor(a1, 32, 64);

    if (g == 0) {
        float v0 = di * a0, v1f = di * a1;
        if (bias) { v0 += bias[col0]; v1f += bias[col0 + 1]; }
        if (relu_flag) { v0 = fmaxf(v0, 0.0f); v1f = fmaxf(v1f, 0.0f); }
        if (out_f) {
            *(float2*)(out_f + (size_t)node * 128 + col0) = make_float2(v0, v1f);
        } else {
            *(uint2*)(out_p + (size_t)node * 128 + col0) =
                make_uint2(pack_hilo(v0), pack_hilo(v1f));
        }
    }
}

// ---------------- bf16-split MFMA GEMM, 128x128 tile ----------------------
// C = A*B (+bias)(relu). A: [M][K] packed hi|lo. Btp: [N][K] packed (B^T).
// Output: Cf (f32) | Cp (packed) | Cb (bf16).
#define TM 128
#define TN 128
#define TK 32
#define LDK 40    // halfs per LDS row: 80B stride -> b128 frag reads 2-way (free)

__global__ __launch_bounds__(256) void mfma_gemm(
        const unsigned* __restrict__ Ap, const unsigned* __restrict__ Btp,
        const float* __restrict__ bias, float* __restrict__ Cf,
        unsigned* __restrict__ Cp, unsigned short* __restrict__ Cb,
        int M, int K, int N, int relu_flag) {
    __shared__ unsigned short smem[4 * 128 * LDK];   // 40 KB
    unsigned short* As_hi = smem;
    unsigned short* As_lo = smem + 128 * LDK;
    unsigned short* Bs_hi = smem + 2 * 128 * LDK;
    unsigned short* Bs_lo = smem + 3 * 128 * LDK;

    int tid = threadIdx.x;
    int lane = tid & 63;
    int wv = tid >> 6;
    int m0w = (wv & 1) * 64;
    int n0w = (wv >> 1) * 64;
    int row0 = blockIdx.x * TM;
    int col0 = blockIdx.y * TN;

    int sr  = tid >> 2;            // 0..63 (staging row)
    int skc = (tid & 3) * 8;       // packed-uint offset within 32-k

    floatx4 acc[4][4];
    #pragma unroll
    for (int i = 0; i < 4; ++i)
        #pragma unroll
        for (int j = 0; j < 4; ++j)
            acc[i][j] = (floatx4){0.f, 0.f, 0.f, 0.f};

    for (int k0 = 0; k0 < K; k0 += TK) {
        uint4 av[2][2], bv[2][2];
        #pragma unroll
        for (int p = 0; p < 2; ++p) {
            int r = sr + p * 64;
            int ar = row0 + r;
            if (ar < M) {
                const uint4* pa = (const uint4*)(Ap + (size_t)ar * K + k0 + skc);
                av[p][0] = pa[0];  av[p][1] = pa[1];
            } else {
                av[p][0] = make_uint4(0, 0, 0, 0);
                av[p][1] = make_uint4(0, 0, 0, 0);
            }
            const uint4* pb = (const uint4*)(Btp + (size_t)(col0 + r) * K + k0 + skc);
            bv[p][0] = pb[0];  bv[p][1] = pb[1];
        }
        __syncthreads();          // prev iter frag reads done
        #pragma unroll
        for (int p = 0; p < 2; ++p) {
            int r = sr + p * 64;
            unsigned ua[8] = {av[p][0].x, av[p][0].y, av[p][0].z, av[p][0].w,
                              av[p][1].x, av[p][1].y, av[p][1].z, av[p][1].w};
            unsigned ub[8] = {bv[p][0].x, bv[p][0].y, bv[p][0].z, bv[p][0].w,
                              bv[p][1].x, bv[p][1].y, bv[p][1].z, bv[p][1].w};
            short8 ahs, als, bhs, bls;
            #pragma unroll
            for (int j = 0; j < 8; ++j) {
                ahs[j] = (short)(ua[j] >> 16);  als[j] = (short)(ua[j] & 0xFFFFu);
                bhs[j] = (short)(ub[j] >> 16);  bls[j] = (short)(ub[j] & 0xFFFFu);
            }
            *(short8*)&As_hi[r * LDK + skc] = ahs;
            *(short8*)&As_lo[r * LDK + skc] = als;
            *(short8*)&Bs_hi[r * LDK + skc] = bhs;
            *(short8*)&Bs_lo[r * LDK + skc] = bls;
        }
        __syncthreads();
        short8 ah[4], al[4], bh[4], bl[4];
        int ka = (lane >> 4) * 8;
        #pragma unroll
        for (int mi = 0; mi < 4; ++mi) {
            int rr = m0w + mi * 16 + (lane & 15);
            ah[mi] = *(const short8*)&As_hi[rr * LDK + ka];
            al[mi] = *(const short8*)&As_lo[rr * LDK + ka];
        }
        #pragma unroll
        for (int ni = 0; ni < 4; ++ni) {
            int cc = n0w + ni * 16 + (lane & 15);
            bh[ni] = *(const short8*)&Bs_hi[cc * LDK + ka];
            bl[ni] = *(const short8*)&Bs_lo[cc * LDK + ka];
        }
        #pragma unroll
        for (int mi = 0; mi < 4; ++mi)
            #pragma unroll
            for (int ni = 0; ni < 4; ++ni) {
                acc[mi][ni] = __builtin_amdgcn_mfma_f32_16x16x32_bf16(al[mi], bh[ni], acc[mi][ni], 0, 0, 0);
                acc[mi][ni] = __builtin_amdgcn_mfma_f32_16x16x32_bf16(ah[mi], bl[ni], acc[mi][ni], 0, 0, 0);
                acc[mi][ni] = __builtin_amdgcn_mfma_f32_16x16x32_bf16(ah[mi], bh[ni], acc[mi][ni], 0, 0, 0);
            }
    }

    // epilogue: C/D mapping col=lane&15, row=(lane>>4)*4+reg
    #pragma unroll
    for (int mi = 0; mi < 4; ++mi) {
        #pragma unroll
        for (int reg = 0; reg < 4; ++reg) {
            int r = row0 + m0w + mi * 16 + (lane >> 4) * 4 + reg;
            if (r < M) {
                #pragma unroll
                for (int ni = 0; ni < 4; ++ni) {
                    int c = col0 + n0w + ni * 16 + (lane & 15);
                    float v = acc[mi][ni][reg];
                    if (bias) v += bias[c];
                    if (relu_flag) v = fmaxf(v, 0.0f);
                    if (Cf)      Cf[(size_t)r * N + c] = v;
                    else if (Cp) Cp[(size_t)r * N + c] = pack_hilo(v);
                    else         Cb[(size_t)r * N + c] = f2bf(v);
                }
            }
        }
    }
}

// ---------------------------------------------------------------------------
extern "C" void kernel_launch(void* const* d_in, const int* in_sizes, int n_in,
                              void* d_out, int out_size, void* d_ws, size_t ws_size,
                              hipStream_t stream) {
    const float* x  = (const float*)d_in[0];
    const int*   ei = (const int*)d_in[1];
    const float* W1 = (const float*)d_in[2];
    const float* b1 = (const float*)d_in[3];
    const float* W2 = (const float*)d_in[4];
    const float* b2 = (const float*)d_in[5];

    const int n = in_sizes[0] / C_IN;          // 50000
    const int E = in_sizes[1] / 2;             // 800000

    const int* src = ei;
    const int* dst = ei + E;

    // workspace layout (~81 MB)
    unsigned short* h2b = (unsigned short*)d_ws;         // n*128 bf16
    unsigned* z1p = (unsigned*)(h2b + (size_t)n * C_OUT);// n*256 packed
    unsigned short* xb = (unsigned short*)(z1p + (size_t)n * C_HID); // n*128 bf16
    unsigned* w1t = (unsigned*)(xb + (size_t)n * C_IN);  // 128*256
    unsigned* w2t = w1t + C_IN * C_HID;                  // 256*128
    float*    dinv = (float*)(w2t + C_HID * C_OUT);      // n
    int* counts  = (int*)(dinv + n);                     // n
    int* offsets = counts + n;                           // n+1
    int* cursor  = offsets + (n + 1);                    // n
    int* csr_src = cursor + n;                           // E (+slack follows)
    int* block_sums = csr_src + E;                       // 64
    int* block_base = block_sums + 64;                   // 64

    unsigned* agg0p = (unsigned*)d_out;    // n*128 packed, overwritten by final out
    float*    outp  = (float*)d_out;

    const int nb = (n + SCHUNK - 1) / SCHUNK;            // 49

    // ---- CSR build ----
    hipMemsetAsync(counts, 0, (size_t)n * sizeof(int), stream);
    deg_kernel<<<(E + 255) / 256, 256, 0, stream>>>(dst, counts, E);
    scan_reduce<<<nb, 256, 0, stream>>>(counts, block_sums, n);
    scan_sums<<<1, 64, 0, stream>>>(block_sums, block_base, nb, offsets, n, E);
    scan_apply<<<nb, 256, 0, stream>>>(counts, block_base, offsets, cursor, dinv, n);
    fill_csr<<<(E + 255) / 256, 256, 0, stream>>>(src, dst, cursor, csr_src, E);

    // ---- casts (tiny) ----
    cast_w_t<<<(C_IN * C_HID + 255) / 256, 256, 0, stream>>>(W1, w1t, C_IN, C_HID);
    cast_w_t<<<(C_HID * C_OUT + 255) / 256, 256, 0, stream>>>(W2, w2t, C_HID, C_OUT);
    {
        int count4 = n * C_IN / 4;
        cast_x_bf16<<<(count4 + 255) / 256, 256, 0, stream>>>(x, (unsigned*)xb, count4);
    }

    const int agg_blocks = 8 * ((n + 7) / 8);            // 50000

    // ---- layer 1: agg0 = Ahat*X (packed) ; z1 = relu(agg0@W1 + b1) (packed) ----
    agg_slice_kernel<<<agg_blocks, 256, 0, stream>>>(xb, offsets, csr_src, dinv,
                                                     nullptr, nullptr, agg0p, 0, n);
    {
        dim3 grid((n + TM - 1) / TM, C_HID / TN);        // (391, 2)
        mfma_gemm<<<grid, 256, 0, stream>>>(agg0p, w1t, b1, nullptr, z1p, nullptr,
                                            n, C_IN, C_HID, 1);
    }

    // ---- layer 2: h2 = z1@W2 (bf16) ; out = relu(Ahat*h2 + b2) ----
    {
        dim3 grid((n + TM - 1) / TM, C_OUT / TN);        // (391, 1)
        mfma_gemm<<<grid, 256, 0, stream>>>(z1p, w2t, nullptr, nullptr, nullptr, h2b,
                                            n, C_HID, C_OUT, 0);
    }
    agg_slice_kernel<<<agg_blocks, 256, 0, stream>>>(h2b, offsets, csr_src, dinv,
                                                     b2, outp, nullptr, 1, n);
}

// Round 8
// 398.986 us; speedup vs baseline: 1.1292x; 1.1292x over previous
//
#include <hip/hip_runtime.h>

// ---------------------------------------------------------------------------
// GCN 2-layer forward on MI355X.
// out = relu(Ahat * relu((Ahat*X)*W1 + b1) * W2 + b2),  Ahat = D^-1/2 (A+I) D^-1/2
// R1: multi-block scan. R2: agg unroll-8; 128x128 fp32 GEMM.
// R3: GEMMs -> bf16-split MFMA (Ootomo 3-mult), packed (hi<<16|lo) operands.
// R4: agg bf16 gather, 1 wave/node, 8x256B in flight (32 lines MLP) -> 57us.
// R5/R7: XCD-sliced agg regressed 2x: unroll-2 64B gathers = 2 lines MLP/wave
//     (VGPR=12), sched_barrier pinned scheduler, idx x4 -> FETCH up.
// R8: slicing WITH MLP: per slice-wave 4 edges/inst x unroll-8 = 32 edges =
//     32 lines in flight (R4-equal); int2{src,dinv} edge records kill the
//     dependent dinv gather; no sched_barrier. cursor aliases counts.
// ---------------------------------------------------------------------------

#define C_IN   128
#define C_HID  256
#define C_OUT  128

typedef __attribute__((ext_vector_type(8))) short short8;
typedef __attribute__((ext_vector_type(4))) float floatx4;

__device__ __forceinline__ unsigned short f2bf(float f) {
    unsigned u = __float_as_uint(f);
    u += 0x7FFFu + ((u >> 16) & 1u);      // RNE
    return (unsigned short)(u >> 16);
}
__device__ __forceinline__ float bf2f(unsigned short b) {
    return __uint_as_float(((unsigned)b) << 16);
}
__device__ __forceinline__ unsigned pack_hilo(float f) {
    unsigned short hi = f2bf(f);
    unsigned short lo = f2bf(f - bf2f(hi));
    return ((unsigned)hi << 16) | (unsigned)lo;
}
__device__ __forceinline__ float bflo(unsigned v) {   // low short as bf16->f32
    return __uint_as_float((v & 0xFFFFu) << 16);
}
__device__ __forceinline__ float bfhi(unsigned v) {   // high short as bf16->f32
    return __uint_as_float(v & 0xFFFF0000u);
}

// ---------------- degree histogram ----------------
__global__ void deg_kernel(const int* __restrict__ dst, int* __restrict__ counts, int E) {
    int e = blockIdx.x * blockDim.x + threadIdx.x;
    if (e < E) atomicAdd(&counts[dst[e]], 1);
}

// ---------------- multi-block scan: 1024 counts per block ----------------
#define SCHUNK 1024

__global__ __launch_bounds__(256) void scan_reduce(const int* __restrict__ counts,
                                                   int* __restrict__ block_sums, int n) {
    int b = blockIdx.x;
    int base = b * SCHUNK;
    int t = threadIdx.x;
    int s = 0;
    #pragma unroll
    for (int u = 0; u < 4; ++u) {
        int i = base + t * 4 + u;
        if (i < n) s += counts[i];
    }
    #pragma unroll
    for (int off = 32; off; off >>= 1) s += __shfl_down(s, off, 64);
    __shared__ int ws[4];
    int wave = t >> 6;
    if ((t & 63) == 0) ws[wave] = s;
    __syncthreads();
    if (t == 0) block_sums[b] = ws[0] + ws[1] + ws[2] + ws[3];
}

__global__ __launch_bounds__(64) void scan_sums(const int* __restrict__ block_sums,
                                                int* __restrict__ block_base, int nb,
                                                int* __restrict__ offsets, int n, int E) {
    int t = threadIdx.x;
    int v = (t < nb) ? block_sums[t] : 0;
    int x = v;
    #pragma unroll
    for (int off = 1; off < 64; off <<= 1) {
        int y = __shfl_up(x, off, 64);
        if (t >= off) x += y;
    }
    if (t < nb) block_base[t] = x - v;
    if (t == 0) offsets[n] = E;
}

// reads counts, writes offsets + cursor (cursor may ALIAS counts: each index
// is read before written by the same owning thread) + fused dinv.
__global__ __launch_bounds__(256) void scan_apply(const int* __restrict__ counts,
                                                  const int* __restrict__ block_base,
                                                  int* __restrict__ offsets,
                                                  int* __restrict__ cursor,
                                                  float* __restrict__ dinv, int n) {
    int b = blockIdx.x;
    int base_i = b * SCHUNK;
    int t = threadIdx.x;
    int c[4];
    #pragma unroll
    for (int u = 0; u < 4; ++u) {
        int i = base_i + t * 4 + u;
        c[u] = (i < n) ? counts[i] : 0;
    }
    int tot = c[0] + c[1] + c[2] + c[3];
    int x = tot;
    int lane = t & 63;
    #pragma unroll
    for (int off = 1; off < 64; off <<= 1) {
        int y = __shfl_up(x, off, 64);
        if (lane >= off) x += y;
    }
    __shared__ int ws[4];
    int wave = t >> 6;
    if (lane == 63) ws[wave] = x;
    __syncthreads();
    int wbase = 0;
    for (int w = 0; w < wave; ++w) wbase += ws[w];
    int run = block_base[b] + wbase + (x - tot);
    #pragma unroll
    for (int u = 0; u < 4; ++u) {
        int i = base_i + t * 4 + u;
        if (i < n) {
            offsets[i] = run;
            cursor[i]  = run;
            dinv[i]    = rsqrtf((float)(c[u] + 1));   // +1 self-loop
            run += c[u];
        }
    }
}

// fill CSR with fused edge records {src, bits(dinv[src])}
__global__ void fill_csr_ew(const int* __restrict__ src, const int* __restrict__ dst,
                            const float* __restrict__ dinv, int* __restrict__ cursor,
                            int2* __restrict__ csr_ew, int E) {
    int e = blockIdx.x * blockDim.x + threadIdx.x;
    if (e < E) {
        int s = src[e];
        float w = dinv[s];
        int p = atomicAdd(&cursor[dst[e]], 1);
        csr_ew[p] = make_int2(s, __float_as_int(w));
    }
}

// ---------------- weight cast+transpose: W[K][N] f32 -> Wt[N][K] packed ----
__global__ void cast_w_t(const float* __restrict__ W, unsigned* __restrict__ Wtp,
                         int K, int N) {
    int idx = blockIdx.x * blockDim.x + threadIdx.x;
    if (idx < K * N) {
        int k = idx / N, nn = idx - k * N;
        Wtp[(size_t)nn * K + k] = pack_hilo(W[idx]);
    }
}

// ---------------- x -> bf16 cast, 4 elems/thread ----------------
__global__ void cast_x_bf16(const float* __restrict__ x, unsigned* __restrict__ xb2,
                            int count4) {
    int idx = blockIdx.x * blockDim.x + threadIdx.x;
    if (idx < count4) {
        float4 f = ((const float4*)x)[idx];
        unsigned lo = (unsigned)f2bf(f.x) | ((unsigned)f2bf(f.y) << 16);
        unsigned hi = (unsigned)f2bf(f.z) | ((unsigned)f2bf(f.w) << 16);
        ((uint2*)xb2)[idx] = make_uint2(lo, hi);
    }
}

// ---------------- XCD-sliced pull aggregation, high-MLP (R8) ----------------
// 4 column-slices of 32 cols (64B lines). blockIdx&7: slice=&3, sub=>>2;
// with blockIdx%8 = XCD round-robin, slice s lives on XCDs {s, s+4} ->
// 3.2MB hb footprint per XCD (L2-resident). Wave = one node's slice.
// Lane = 16*g + c: edge-subgroup g (4 edges/inst), c = uint within slice.
// Inner loop: 32 edges (8 gather insts = 32 lines) in flight per wave.
// Cross-group combine via shfl_xor(16/32); self term in g==0 only.
// csr_ew has >=32 int2 slack past E.
__global__ __launch_bounds__(256) void agg_slice_kernel(
        const unsigned short* __restrict__ hb, const int* __restrict__ offsets,
        const int2* __restrict__ csr_ew, const float* __restrict__ dinv,
        const float* __restrict__ bias, float* __restrict__ out_f,
        unsigned* __restrict__ out_p, int relu_flag, int n) {
    int xb7  = blockIdx.x & 7;
    int slice = xb7 & 3;
    int node = (blockIdx.x >> 3) * 8 + (xb7 >> 2) * 4 + (threadIdx.x >> 6);
    if (node >= n) return;
    int lane = threadIdx.x & 63;
    int g = lane >> 4;                 // edge subgroup 0..3
    int c = lane & 15;                 // uint within 64B slice
    int sloff = slice * 16 + c;        // uint offset within 64-uint row
    int col0 = slice * 32 + c * 2;

    const unsigned* hrow = (const unsigned*)hb;   // row j = 64 uints

    float di = dinv[node];
    float selfw = (g == 0) ? di : 0.0f;           // self term counted ONCE
    unsigned sv = hrow[(size_t)node * 64 + sloff];
    float a0 = selfw * bflo(sv);
    float a1 = selfw * bfhi(sv);

    int lo = offsets[node], hi = offsets[node + 1];
    for (int k = lo; k < hi; k += 32) {
        int jj[8]; float w[8];
        #pragma unroll
        for (int u = 0; u < 8; ++u) {
            int kk = k + u * 4 + g;
            int2 rec = csr_ew[kk];                // slack past E covers overrun
            bool ok = kk < hi;
            jj[u] = ok ? rec.x : 0;
            w[u]  = ok ? __int_as_float(rec.y) : 0.0f;
        }
        unsigned v[8];
        #pragma unroll
        for (int u = 0; u < 8; ++u)
            v[u] = hrow[(size_t)jj[u] * 64 + sloff];
        #pragma unroll
        for (int u = 0; u < 8; ++u) {
            a0 += w[u] * bflo(v[u]);
            a1 += w[u] * bfhi(v[u]);
        }
    }

    // combine edge subgroups: xor16 (g bit0), xor32 (g bit1)
    a0 += __shfl_xor(a0, 16, 64);  a1 += __shfl_xor(a1, 16, 64);
    a0 += __shfl_xor(a0, 32, 64);  a1 += __shfl_xor(a1, 32, 64);

    if (g == 0) {
        float v0 = di * a0, v1f = di * a1;
        if (bias) { v0 += bias[col0]; v1f += bias[col0 + 1]; }
        if (relu_flag) { v0 = fmaxf(v0, 0.0f); v1f = fmaxf(v1f, 0.0f); }
        if (out_f) {
            *(float2*)(out_f + (size_t)node * 128 + col0) = make_float2(v0, v1f);
        } else {
            *(uint2*)(out_p + (size_t)node * 128 + col0) =
                make_uint2(pack_hilo(v0), pack_hilo(v1f));
        }
    }
}

// ---------------- bf16-split MFMA GEMM, 128x128 tile ----------------------
// C = A*B (+bias)(relu). A: [M][K] packed hi|lo. Btp: [N][K] packed (B^T).
// Output: Cf (f32) | Cp (packed) | Cb (bf16).
#define TM 128
#define TN 128
#define TK 32
#define LDK 40    // halfs per LDS row: 80B stride -> b128 frag reads 2-way (free)

__global__ __launch_bounds__(256) void mfma_gemm(
        const unsigned* __restrict__ Ap, const unsigned* __restrict__ Btp,
        const float* __restrict__ bias, float* __restrict__ Cf,
        unsigned* __restrict__ Cp, unsigned short* __restrict__ Cb,
        int M, int K, int N, int relu_flag) {
    __shared__ unsigned short smem[4 * 128 * LDK];   // 40 KB
    unsigned short* As_hi = smem;
    unsigned short* As_lo = smem + 128 * LDK;
    unsigned short* Bs_hi = smem + 2 * 128 * LDK;
    unsigned short* Bs_lo = smem + 3 * 128 * LDK;

    int tid = threadIdx.x;
    int lane = tid & 63;
    int wv = tid >> 6;
    int m0w = (wv & 1) * 64;
    int n0w = (wv >> 1) * 64;
    int row0 = blockIdx.x * TM;
    int col0 = blockIdx.y * TN;

    int sr  = tid >> 2;            // 0..63 (staging row)
    int skc = (tid & 3) * 8;       // packed-uint offset within 32-k

    floatx4 acc[4][4];
    #pragma unroll
    for (int i = 0; i < 4; ++i)
        #pragma unroll
        for (int j = 0; j < 4; ++j)
            acc[i][j] = (floatx4){0.f, 0.f, 0.f, 0.f};

    for (int k0 = 0; k0 < K; k0 += TK) {
        uint4 av[2][2], bv[2][2];
        #pragma unroll
        for (int p = 0; p < 2; ++p) {
            int r = sr + p * 64;
            int ar = row0 + r;
            if (ar < M) {
                const uint4* pa = (const uint4*)(Ap + (size_t)ar * K + k0 + skc);
                av[p][0] = pa[0];  av[p][1] = pa[1];
            } else {
                av[p][0] = make_uint4(0, 0, 0, 0);
                av[p][1] = make_uint4(0, 0, 0, 0);
            }
            const uint4* pb = (const uint4*)(Btp + (size_t)(col0 + r) * K + k0 + skc);
            bv[p][0] = pb[0];  bv[p][1] = pb[1];
        }
        __syncthreads();          // prev iter frag reads done
        #pragma unroll
        for (int p = 0; p < 2; ++p) {
            int r = sr + p * 64;
            unsigned ua[8] = {av[p][0].x, av[p][0].y, av[p][0].z, av[p][0].w,
                              av[p][1].x, av[p][1].y, av[p][1].z, av[p][1].w};
            unsigned ub[8] = {bv[p][0].x, bv[p][0].y, bv[p][0].z, bv[p][0].w,
                              bv[p][1].x, bv[p][1].y, bv[p][1].z, bv[p][1].w};
            short8 ahs, als, bhs, bls;
            #pragma unroll
            for (int j = 0; j < 8; ++j) {
                ahs[j] = (short)(ua[j] >> 16);  als[j] = (short)(ua[j] & 0xFFFFu);
                bhs[j] = (short)(ub[j] >> 16);  bls[j] = (short)(ub[j] & 0xFFFFu);
            }
            *(short8*)&As_hi[r * LDK + skc] = ahs;
            *(short8*)&As_lo[r * LDK + skc] = als;
            *(short8*)&Bs_hi[r * LDK + skc] = bhs;
            *(short8*)&Bs_lo[r * LDK + skc] = bls;
        }
        __syncthreads();
        short8 ah[4], al[4], bh[4], bl[4];
        int ka = (lane >> 4) * 8;
        #pragma unroll
        for (int mi = 0; mi < 4; ++mi) {
            int rr = m0w + mi * 16 + (lane & 15);
            ah[mi] = *(const short8*)&As_hi[rr * LDK + ka];
            al[mi] = *(const short8*)&As_lo[rr * LDK + ka];
        }
        #pragma unroll
        for (int ni = 0; ni < 4; ++ni) {
            int cc = n0w + ni * 16 + (lane & 15);
            bh[ni] = *(const short8*)&Bs_hi[cc * LDK + ka];
            bl[ni] = *(const short8*)&Bs_lo[cc * LDK + ka];
        }
        #pragma unroll
        for (int mi = 0; mi < 4; ++mi)
            #pragma unroll
            for (int ni = 0; ni < 4; ++ni) {
                acc[mi][ni] = __builtin_amdgcn_mfma_f32_16x16x32_bf16(al[mi], bh[ni], acc[mi][ni], 0, 0, 0);
                acc[mi][ni] = __builtin_amdgcn_mfma_f32_16x16x32_bf16(ah[mi], bl[ni], acc[mi][ni], 0, 0, 0);
                acc[mi][ni] = __builtin_amdgcn_mfma_f32_16x16x32_bf16(ah[mi], bh[ni], acc[mi][ni], 0, 0, 0);
            }
    }

    // epilogue: C/D mapping col=lane&15, row=(lane>>4)*4+reg
    #pragma unroll
    for (int mi = 0; mi < 4; ++mi) {
        #pragma unroll
        for (int reg = 0; reg < 4; ++reg) {
            int r = row0 + m0w + mi * 16 + (lane >> 4) * 4 + reg;
            if (r < M) {
                #pragma unroll
                for (int ni = 0; ni < 4; ++ni) {
                    int c = col0 + n0w + ni * 16 + (lane & 15);
                    float v = acc[mi][ni][reg];
                    if (bias) v += bias[c];
                    if (relu_flag) v = fmaxf(v, 0.0f);
                    if (Cf)      Cf[(size_t)r * N + c] = v;
                    else if (Cp) Cp[(size_t)r * N + c] = pack_hilo(v);
                    else         Cb[(size_t)r * N + c] = f2bf(v);
                }
            }
        }
    }
}

// ---------------------------------------------------------------------------
extern "C" void kernel_launch(void* const* d_in, const int* in_sizes, int n_in,
                              void* d_out, int out_size, void* d_ws, size_t ws_size,
                              hipStream_t stream) {
    const float* x  = (const float*)d_in[0];
    const int*   ei = (const int*)d_in[1];
    const float* W1 = (const float*)d_in[2];
    const float* b1 = (const float*)d_in[3];
    const float* W2 = (const float*)d_in[4];
    const float* b2 = (const float*)d_in[5];

    const int n = in_sizes[0] / C_IN;          // 50000
    const int E = in_sizes[1] / 2;             // 800000

    const int* src = ei;
    const int* dst = ei + E;

    // workspace layout (~84 MB)
    unsigned short* h2b = (unsigned short*)d_ws;         // n*128 bf16
    unsigned* z1p = (unsigned*)(h2b + (size_t)n * C_OUT);// n*256 packed
    unsigned short* xb = (unsigned short*)(z1p + (size_t)n * C_HID); // n*128 bf16
    unsigned* w1t = (unsigned*)(xb + (size_t)n * C_IN);  // 128*256
    unsigned* w2t = w1t + C_IN * C_HID;                  // 256*128
    float*    dinv = (float*)(w2t + C_HID * C_OUT);      // n
    int* counts  = (int*)(dinv + n);                     // n (aliased as cursor)
    int* cursor  = counts;                               // alias (safe: see scan_apply)
    int* offsets = counts + n;                           // n+1
    int2* csr_ew = (int2*)(offsets + (n + 1) + 1);       // E int2 (+64 slack)
    int* block_sums = (int*)(csr_ew + E + 64);           // 64
    int* block_base = block_sums + 64;                   // 64

    unsigned* agg0p = (unsigned*)d_out;    // n*128 packed, overwritten by final out
    float*    outp  = (float*)d_out;

    const int nb = (n + SCHUNK - 1) / SCHUNK;            // 49

    // ---- CSR build ----
    hipMemsetAsync(counts, 0, (size_t)n * sizeof(int), stream);
    deg_kernel<<<(E + 255) / 256, 256, 0, stream>>>(dst, counts, E);
    scan_reduce<<<nb, 256, 0, stream>>>(counts, block_sums, n);
    scan_sums<<<1, 64, 0, stream>>>(block_sums, block_base, nb, offsets, n, E);
    scan_apply<<<nb, 256, 0, stream>>>(counts, block_base, offsets, cursor, dinv, n);
    fill_csr_ew<<<(E + 255) / 256, 256, 0, stream>>>(src, dst, dinv, cursor, csr_ew, E);

    // ---- casts (tiny) ----
    cast_w_t<<<(C_IN * C_HID + 255) / 256, 256, 0, stream>>>(W1, w1t, C_IN, C_HID);
    cast_w_t<<<(C_HID * C_OUT + 255) / 256, 256, 0, stream>>>(W2, w2t, C_HID, C_OUT);
    {
        int count4 = n * C_IN / 4;
        cast_x_bf16<<<(count4 + 255) / 256, 256, 0, stream>>>(x, (unsigned*)xb, count4);
    }

    const int agg_blocks = 8 * ((n + 7) / 8);            // 50000

    // ---- layer 1: agg0 = Ahat*X (packed) ; z1 = relu(agg0@W1 + b1) (packed) ----
    agg_slice_kernel<<<agg_blocks, 256, 0, stream>>>(xb, offsets, csr_ew, dinv,
                                                     nullptr, nullptr, agg0p, 0, n);
    {
        dim3 grid((n + TM - 1) / TM, C_HID / TN);        // (391, 2)
        mfma_gemm<<<grid, 256, 0, stream>>>(agg0p, w1t, b1, nullptr, z1p, nullptr,
                                            n, C_IN, C_HID, 1);
    }

    // ---- layer 2: h2 = z1@W2 (bf16) ; out = relu(Ahat*h2 + b2) ----
    {
        dim3 grid((n + TM - 1) / TM, C_OUT / TN);        // (391, 1)
        mfma_gemm<<<grid, 256, 0, stream>>>(z1p, w2t, nullptr, nullptr, nullptr, h2b,
                                            n, C_HID, C_OUT, 0);
    }
    agg_slice_kernel<<<agg_blocks, 256, 0, stream>>>(h2b, offsets, csr_ew, dinv,
                                                     b2, outp, nullptr, 1, n);
}

// Round 9
// 336.378 us; speedup vs baseline: 1.3394x; 1.1861x over previous
//
#include <hip/hip_runtime.h>

// ---------------------------------------------------------------------------
// GCN 2-layer forward on MI355X.
// out = relu(Ahat * relu((Ahat*X)*W1 + b1) * W2 + b2),  Ahat = D^-1/2 (A+I) D^-1/2
// R1: multi-block scan. R2: agg unroll-8; 128x128 fp32 GEMM.
// R3: GEMMs -> bf16-split MFMA (Ootomo 3-mult), packed (hi<<16|lo) operands.
// R4: agg bf16 gather, wave/node, 8x256B rows in flight -> 57us (best agg).
// R5-R8: XCD column-slicing falsified twice (FETCH never dropped; 4x VALU tax
//     from 4 slice-waves/node). Keep only the int2{src,dinv} edge records.
// R9: R4 shape + edge records (chain 3->2 random loads, -1/3 VMEM insts)
//     + software-pipelined rec prefetch (batch cost ~ one gather latency)
//     + nontemporal rec loads/output stores (keep hb resident in L2).
// ---------------------------------------------------------------------------

#define C_IN   128
#define C_HID  256
#define C_OUT  128

typedef __attribute__((ext_vector_type(8))) short short8;
typedef __attribute__((ext_vector_type(4))) float floatx4;

__device__ __forceinline__ unsigned short f2bf(float f) {
    unsigned u = __float_as_uint(f);
    u += 0x7FFFu + ((u >> 16) & 1u);      // RNE
    return (unsigned short)(u >> 16);
}
__device__ __forceinline__ float bf2f(unsigned short b) {
    return __uint_as_float(((unsigned)b) << 16);
}
__device__ __forceinline__ unsigned pack_hilo(float f) {
    unsigned short hi = f2bf(f);
    unsigned short lo = f2bf(f - bf2f(hi));
    return ((unsigned)hi << 16) | (unsigned)lo;
}
__device__ __forceinline__ float bflo(unsigned v) {   // low short as bf16->f32
    return __uint_as_float((v & 0xFFFFu) << 16);
}
__device__ __forceinline__ float bfhi(unsigned v) {   // high short as bf16->f32
    return __uint_as_float(v & 0xFFFF0000u);
}

// ---------------- degree histogram ----------------
__global__ void deg_kernel(const int* __restrict__ dst, int* __restrict__ counts, int E) {
    int e = blockIdx.x * blockDim.x + threadIdx.x;
    if (e < E) atomicAdd(&counts[dst[e]], 1);
}

// ---------------- multi-block scan: 1024 counts per block ----------------
#define SCHUNK 1024

__global__ __launch_bounds__(256) void scan_reduce(const int* __restrict__ counts,
                                                   int* __restrict__ block_sums, int n) {
    int b = blockIdx.x;
    int base = b * SCHUNK;
    int t = threadIdx.x;
    int s = 0;
    #pragma unroll
    for (int u = 0; u < 4; ++u) {
        int i = base + t * 4 + u;
        if (i < n) s += counts[i];
    }
    #pragma unroll
    for (int off = 32; off; off >>= 1) s += __shfl_down(s, off, 64);
    __shared__ int ws[4];
    int wave = t >> 6;
    if ((t & 63) == 0) ws[wave] = s;
    __syncthreads();
    if (t == 0) block_sums[b] = ws[0] + ws[1] + ws[2] + ws[3];
}

__global__ __launch_bounds__(64) void scan_sums(const int* __restrict__ block_sums,
                                                int* __restrict__ block_base, int nb,
                                                int* __restrict__ offsets, int n, int E) {
    int t = threadIdx.x;
    int v = (t < nb) ? block_sums[t] : 0;
    int x = v;
    #pragma unroll
    for (int off = 1; off < 64; off <<= 1) {
        int y = __shfl_up(x, off, 64);
        if (t >= off) x += y;
    }
    if (t < nb) block_base[t] = x - v;
    if (t == 0) offsets[n] = E;
}

// reads counts, writes offsets + cursor (cursor ALIASES counts: each index is
// read before written by the same owning thread) + fused dinv.
__global__ __launch_bounds__(256) void scan_apply(const int* __restrict__ counts,
                                                  const int* __restrict__ block_base,
                                                  int* __restrict__ offsets,
                                                  int* __restrict__ cursor,
                                                  float* __restrict__ dinv, int n) {
    int b = blockIdx.x;
    int base_i = b * SCHUNK;
    int t = threadIdx.x;
    int c[4];
    #pragma unroll
    for (int u = 0; u < 4; ++u) {
        int i = base_i + t * 4 + u;
        c[u] = (i < n) ? counts[i] : 0;
    }
    int tot = c[0] + c[1] + c[2] + c[3];
    int x = tot;
    int lane = t & 63;
    #pragma unroll
    for (int off = 1; off < 64; off <<= 1) {
        int y = __shfl_up(x, off, 64);
        if (lane >= off) x += y;
    }
    __shared__ int ws[4];
    int wave = t >> 6;
    if (lane == 63) ws[wave] = x;
    __syncthreads();
    int wbase = 0;
    for (int w = 0; w < wave; ++w) wbase += ws[w];
    int run = block_base[b] + wbase + (x - tot);
    #pragma unroll
    for (int u = 0; u < 4; ++u) {
        int i = base_i + t * 4 + u;
        if (i < n) {
            offsets[i] = run;
            cursor[i]  = run;
            dinv[i]    = rsqrtf((float)(c[u] + 1));   // +1 self-loop
            run += c[u];
        }
    }
}

// fill CSR with fused edge records {src, bits(dinv[src])}
__global__ void fill_csr_ew(const int* __restrict__ src, const int* __restrict__ dst,
                            const float* __restrict__ dinv, int* __restrict__ cursor,
                            int2* __restrict__ csr_ew, int E) {
    int e = blockIdx.x * blockDim.x + threadIdx.x;
    if (e < E) {
        int s = src[e];
        float w = dinv[s];
        int p = atomicAdd(&cursor[dst[e]], 1);
        csr_ew[p] = make_int2(s, __float_as_int(w));
    }
}

// ---------------- weight cast+transpose: W[K][N] f32 -> Wt[N][K] packed ----
__global__ void cast_w_t(const float* __restrict__ W, unsigned* __restrict__ Wtp,
                         int K, int N) {
    int idx = blockIdx.x * blockDim.x + threadIdx.x;
    if (idx < K * N) {
        int k = idx / N, nn = idx - k * N;
        Wtp[(size_t)nn * K + k] = pack_hilo(W[idx]);
    }
}

// ---------------- x -> bf16 cast, 4 elems/thread ----------------
__global__ void cast_x_bf16(const float* __restrict__ x, unsigned* __restrict__ xb2,
                            int count4) {
    int idx = blockIdx.x * blockDim.x + threadIdx.x;
    if (idx < count4) {
        float4 f = ((const float4*)x)[idx];
        unsigned lo = (unsigned)f2bf(f.x) | ((unsigned)f2bf(f.y) << 16);
        unsigned hi = (unsigned)f2bf(f.z) | ((unsigned)f2bf(f.w) << 16);
        ((uint2*)xb2)[idx] = make_uint2(lo, hi);
    }
}

// ---------------- pull aggregation (R9): wave/node, pipelined records -------
// Wave = node; lane covers 2 cols (one uint of the 256B bf16 row -> each edge
// gather is one 256B wave txn, 4 lines). Batch of 8 edges in flight; next
// batch's records prefetched (nontemporal) during current gathers. Output
// stored nontemporal (don't evict hb from L2). csr_ew has >=16 recs slack.
__global__ __launch_bounds__(256) void agg_kernel(
        const unsigned short* __restrict__ hb, const int* __restrict__ offsets,
        const long long* __restrict__ csr_ew, const float* __restrict__ dinv,
        const float* __restrict__ bias, float* __restrict__ out_f,
        unsigned* __restrict__ out_p, int relu_flag, int n) {
    int node = blockIdx.x * 4 + (threadIdx.x >> 6);
    if (node >= n) return;
    int lane = threadIdx.x & 63;

    const unsigned* hrow = (const unsigned*)hb;   // row j = 64 uints
    float di = dinv[node];
    unsigned sv = hrow[(size_t)node * 64 + lane];
    float a0 = di * bflo(sv);
    float a1 = di * bfhi(sv);

    int lo = offsets[node], hi = offsets[node + 1];

    long long rec[8];
    #pragma unroll
    for (int u = 0; u < 8; ++u)
        rec[u] = __builtin_nontemporal_load(&csr_ew[lo + u]);   // slack covers deg==0

    for (int k = lo; k < hi; k += 8) {
        int jj[8]; float w[8];
        #pragma unroll
        for (int u = 0; u < 8; ++u) {
            bool ok = (k + u) < hi;
            jj[u] = ok ? (int)rec[u] : 0;                       // low 32 = src
            w[u]  = ok ? __int_as_float((int)(rec[u] >> 32)) : 0.0f;
        }
        unsigned v[8];
        #pragma unroll
        for (int u = 0; u < 8; ++u)
            v[u] = hrow[(size_t)jj[u] * 64 + lane];
        #pragma unroll
        for (int u = 0; u < 8; ++u)                             // prefetch next batch
            rec[u] = __builtin_nontemporal_load(&csr_ew[k + 8 + u]);
        #pragma unroll
        for (int u = 0; u < 8; ++u) {
            a0 += w[u] * bflo(v[u]);
            a1 += w[u] * bfhi(v[u]);
        }
    }

    int c0 = lane * 2;
    float v0 = di * a0, v1f = di * a1;
    if (bias) { v0 += bias[c0]; v1f += bias[c0 + 1]; }
    if (relu_flag) { v0 = fmaxf(v0, 0.0f); v1f = fmaxf(v1f, 0.0f); }
    if (out_f) {
        unsigned long long ov = ((unsigned long long)__float_as_uint(v1f) << 32)
                              | (unsigned long long)__float_as_uint(v0);
        __builtin_nontemporal_store(ov, (unsigned long long*)(out_f + (size_t)node * 128 + c0));
    } else {
        unsigned long long ov = ((unsigned long long)pack_hilo(v1f) << 32)
                              | (unsigned long long)pack_hilo(v0);
        __builtin_nontemporal_store(ov, (unsigned long long*)(out_p + (size_t)node * 128 + c0));
    }
}

// ---------------- bf16-split MFMA GEMM, 128x128 tile ----------------------
// C = A*B (+bias)(relu). A: [M][K] packed hi|lo. Btp: [N][K] packed (B^T).
// Output: Cf (f32) | Cp (packed) | Cb (bf16).
#define TM 128
#define TN 128
#define TK 32
#define LDK 40    // halfs per LDS row: 80B stride -> b128 frag reads 2-way (free)

__global__ __launch_bounds__(256) void mfma_gemm(
        const unsigned* __restrict__ Ap, const unsigned* __restrict__ Btp,
        const float* __restrict__ bias, float* __restrict__ Cf,
        unsigned* __restrict__ Cp, unsigned short* __restrict__ Cb,
        int M, int K, int N, int relu_flag) {
    __shared__ unsigned short smem[4 * 128 * LDK];   // 40 KB
    unsigned short* As_hi = smem;
    unsigned short* As_lo = smem + 128 * LDK;
    unsigned short* Bs_hi = smem + 2 * 128 * LDK;
    unsigned short* Bs_lo = smem + 3 * 128 * LDK;

    int tid = threadIdx.x;
    int lane = tid & 63;
    int wv = tid >> 6;
    int m0w = (wv & 1) * 64;
    int n0w = (wv >> 1) * 64;
    int row0 = blockIdx.x * TM;
    int col0 = blockIdx.y * TN;

    int sr  = tid >> 2;            // 0..63 (staging row)
    int skc = (tid & 3) * 8;       // packed-uint offset within 32-k

    floatx4 acc[4][4];
    #pragma unroll
    for (int i = 0; i < 4; ++i)
        #pragma unroll
        for (int j = 0; j < 4; ++j)
            acc[i][j] = (floatx4){0.f, 0.f, 0.f, 0.f};

    for (int k0 = 0; k0 < K; k0 += TK) {
        uint4 av[2][2], bv[2][2];
        #pragma unroll
        for (int p = 0; p < 2; ++p) {
            int r = sr + p * 64;
            int ar = row0 + r;
            if (ar < M) {
                const uint4* pa = (const uint4*)(Ap + (size_t)ar * K + k0 + skc);
                av[p][0] = pa[0];  av[p][1] = pa[1];
            } else {
                av[p][0] = make_uint4(0, 0, 0, 0);
                av[p][1] = make_uint4(0, 0, 0, 0);
            }
            const uint4* pb = (const uint4*)(Btp + (size_t)(col0 + r) * K + k0 + skc);
            bv[p][0] = pb[0];  bv[p][1] = pb[1];
        }
        __syncthreads();          // prev iter frag reads done
        #pragma unroll
        for (int p = 0; p < 2; ++p) {
            int r = sr + p * 64;
            unsigned ua[8] = {av[p][0].x, av[p][0].y, av[p][0].z, av[p][0].w,
                              av[p][1].x, av[p][1].y, av[p][1].z, av[p][1].w};
            unsigned ub[8] = {bv[p][0].x, bv[p][0].y, bv[p][0].z, bv[p][0].w,
                              bv[p][1].x, bv[p][1].y, bv[p][1].z, bv[p][1].w};
            short8 ahs, als, bhs, bls;
            #pragma unroll
            for (int j = 0; j < 8; ++j) {
                ahs[j] = (short)(ua[j] >> 16);  als[j] = (short)(ua[j] & 0xFFFFu);
                bhs[j] = (short)(ub[j] >> 16);  bls[j] = (short)(ub[j] & 0xFFFFu);
            }
            *(short8*)&As_hi[r * LDK + skc] = ahs;
            *(short8*)&As_lo[r * LDK + skc] = als;
            *(short8*)&Bs_hi[r * LDK + skc] = bhs;
            *(short8*)&Bs_lo[r * LDK + skc] = bls;
        }
        __syncthreads();
        short8 ah[4], al[4], bh[4], bl[4];
        int ka = (lane >> 4) * 8;
        #pragma unroll
        for (int mi = 0; mi < 4; ++mi) {
            int rr = m0w + mi * 16 + (lane & 15);
            ah[mi] = *(const short8*)&As_hi[rr * LDK + ka];
            al[mi] = *(const short8*)&As_lo[rr * LDK + ka];
        }
        #pragma unroll
        for (int ni = 0; ni < 4; ++ni) {
            int cc = n0w + ni * 16 + (lane & 15);
            bh[ni] = *(const short8*)&Bs_hi[cc * LDK + ka];
            bl[ni] = *(const short8*)&Bs_lo[cc * LDK + ka];
        }
        #pragma unroll
        for (int mi = 0; mi < 4; ++mi)
            #pragma unroll
            for (int ni = 0; ni < 4; ++ni) {
                acc[mi][ni] = __builtin_amdgcn_mfma_f32_16x16x32_bf16(al[mi], bh[ni], acc[mi][ni], 0, 0, 0);
                acc[mi][ni] = __builtin_amdgcn_mfma_f32_16x16x32_bf16(ah[mi], bl[ni], acc[mi][ni], 0, 0, 0);
                acc[mi][ni] = __builtin_amdgcn_mfma_f32_16x16x32_bf16(ah[mi], bh[ni], acc[mi][ni], 0, 0, 0);
            }
    }

    // epilogue: C/D mapping col=lane&15, row=(lane>>4)*4+reg
    #pragma unroll
    for (int mi = 0; mi < 4; ++mi) {
        #pragma unroll
        for (int reg = 0; reg < 4; ++reg) {
            int r = row0 + m0w + mi * 16 + (lane >> 4) * 4 + reg;
            if (r < M) {
                #pragma unroll
                for (int ni = 0; ni < 4; ++ni) {
                    int c = col0 + n0w + ni * 16 + (lane & 15);
                    float v = acc[mi][ni][reg];
                    if (bias) v += bias[c];
                    if (relu_flag) v = fmaxf(v, 0.0f);
                    if (Cf)      Cf[(size_t)r * N + c] = v;
                    else if (Cp) Cp[(size_t)r * N + c] = pack_hilo(v);
                    else         Cb[(size_t)r * N + c] = f2bf(v);
                }
            }
        }
    }
}

// ---------------------------------------------------------------------------
extern "C" void kernel_launch(void* const* d_in, const int* in_sizes, int n_in,
                              void* d_out, int out_size, void* d_ws, size_t ws_size,
                              hipStream_t stream) {
    const float* x  = (const float*)d_in[0];
    const int*   ei = (const int*)d_in[1];
    const float* W1 = (const float*)d_in[2];
    const float* b1 = (const float*)d_in[3];
    const float* W2 = (const float*)d_in[4];
    const float* b2 = (const float*)d_in[5];

    const int n = in_sizes[0] / C_IN;          // 50000
    const int E = in_sizes[1] / 2;             // 800000

    const int* src = ei;
    const int* dst = ei + E;

    // workspace layout (~84 MB)
    unsigned short* h2b = (unsigned short*)d_ws;         // n*128 bf16
    unsigned* z1p = (unsigned*)(h2b + (size_t)n * C_OUT);// n*256 packed
    unsigned short* xb = (unsigned short*)(z1p + (size_t)n * C_HID); // n*128 bf16
    unsigned* w1t = (unsigned*)(xb + (size_t)n * C_IN);  // 128*256
    unsigned* w2t = w1t + C_IN * C_HID;                  // 256*128
    float*    dinv = (float*)(w2t + C_HID * C_OUT);      // n
    int* counts  = (int*)(dinv + n);                     // n (aliased as cursor)
    int* cursor  = counts;                               // alias (safe: see scan_apply)
    int* offsets = counts + n;                           // n+1
    int2* csr_ew = (int2*)(offsets + (n + 1) + 1);       // E int2 (+64 slack), 8B-aligned
    int* block_sums = (int*)(csr_ew + E + 64);           // 64
    int* block_base = block_sums + 64;                   // 64

    unsigned* agg0p = (unsigned*)d_out;    // n*128 packed, overwritten by final out
    float*    outp  = (float*)d_out;

    const int nb = (n + SCHUNK - 1) / SCHUNK;            // 49

    // ---- CSR build ----
    hipMemsetAsync(counts, 0, (size_t)n * sizeof(int), stream);
    deg_kernel<<<(E + 255) / 256, 256, 0, stream>>>(dst, counts, E);
    scan_reduce<<<nb, 256, 0, stream>>>(counts, block_sums, n);
    scan_sums<<<1, 64, 0, stream>>>(block_sums, block_base, nb, offsets, n, E);
    scan_apply<<<nb, 256, 0, stream>>>(counts, block_base, offsets, cursor, dinv, n);
    fill_csr_ew<<<(E + 255) / 256, 256, 0, stream>>>(src, dst, dinv, cursor, csr_ew, E);

    // ---- casts (tiny) ----
    cast_w_t<<<(C_IN * C_HID + 255) / 256, 256, 0, stream>>>(W1, w1t, C_IN, C_HID);
    cast_w_t<<<(C_HID * C_OUT + 255) / 256, 256, 0, stream>>>(W2, w2t, C_HID, C_OUT);
    {
        int count4 = n * C_IN / 4;
        cast_x_bf16<<<(count4 + 255) / 256, 256, 0, stream>>>(x, (unsigned*)xb, count4);
    }

    const int agg_blocks = (n + 3) / 4;

    // ---- layer 1: agg0 = Ahat*X (packed) ; z1 = relu(agg0@W1 + b1) (packed) ----
    agg_kernel<<<agg_blocks, 256, 0, stream>>>(xb, offsets, (const long long*)csr_ew,
                                               dinv, nullptr, nullptr, agg0p, 0, n);
    {
        dim3 grid((n + TM - 1) / TM, C_HID / TN);        // (391, 2)
        mfma_gemm<<<grid, 256, 0, stream>>>(agg0p, w1t, b1, nullptr, z1p, nullptr,
                                            n, C_IN, C_HID, 1);
    }

    // ---- layer 2: h2 = z1@W2 (bf16) ; out = relu(Ahat*h2 + b2) ----
    {
        dim3 grid((n + TM - 1) / TM, C_OUT / TN);        // (391, 1)
        mfma_gemm<<<grid, 256, 0, stream>>>(z1p, w2t, nullptr, nullptr, nullptr, h2b,
                                            n, C_HID, C_OUT, 0);
    }
    agg_kernel<<<agg_blocks, 256, 0, stream>>>(h2b, offsets, (const long long*)csr_ew,
                                               dinv, b2, outp, nullptr, 1, n);
}